// Round 7
// baseline (131.998 us; speedup 1.0000x reference)
//
#include <hip/hip_runtime.h>
#include <cstdint>

using short8 = __attribute__((ext_vector_type(8))) short;
using f32x4  = __attribute__((ext_vector_type(4))) float;

__device__ __forceinline__ uint16_t f2bf(float x) {
    uint32_t u = __float_as_uint(x);
    uint32_t r = (u + 0x7FFFu + ((u >> 16) & 1u)) >> 16;
    return (uint16_t)r;
}
__device__ __forceinline__ int fdiv7(int a) {
    int q = a / 7;
    if ((a % 7 != 0) && (a < 0)) q--;
    return q;
}

// ---------------- merged prep: decode | cfb | wsmall | w1f (round-6 verified, unchanged) ----------------
__global__ void __launch_bounds__(256) k_prep(const float* __restrict__ regcls,
                                              const float* __restrict__ wan,
                                              const float* __restrict__ han,
                                              const float* __restrict__ xan,
                                              const float* __restrict__ yan,
                                              const float* __restrict__ cf,
                                              const float* __restrict__ w1,
                                              const float* __restrict__ w2,
                                              const float* __restrict__ w3,
                                              const float* __restrict__ w4,
                                              int8_t* __restrict__ cells,
                                              uint16_t* __restrict__ cfb,
                                              uint16_t* __restrict__ w1f,
                                              float* __restrict__ w2t,
                                              float* __restrict__ w34t) {
    __shared__ __align__(16) uint16_t lh[16 * 788];   // 25,216 B (w1f branch only)
    int blk = blockIdx.x;
    int t = threadIdx.x;

    if (blk < 5) {
        // ---- ROI decode ----
        int r = blk * 256 + t;
        if (r >= 1250) return;
        int b = r / 625, n = r - b * 625;
        const float* rc = regcls + b * 3125 + n;
        float t0 = rc[0], t1 = rc[625], t2 = rc[1250], t3 = rc[1875];
        float wa = wan[n], ha = han[n], xa = xan[n], ya = yan[n];
        float wr = expf(t2) * wa, hr = expf(t3) * ha;
        float xr = t0 * wa + xa, yr = t1 * ha + ya;
        float xis = xr - wr * 0.5f, yis = yr - hr * 0.5f;
        float xfs = xr + wr * 0.5f, yfs = yr + hr * 0.5f;
        bool valid = (xis < 296.f) && (yis < 296.f) && (xfs >= 0.f) && (yfs >= 0.f);
        int c0 = (int)floorf(fmaxf(xis, 0.f));
        int c1 = (int)floorf(fmaxf(yis, 0.f));
        int c2 = (int)fminf(ceilf(xfs), 295.f);
        int c3 = (int)fmaxf(ceilf(yfs), 295.f);
        const int  XL1[17]    = {294,292,146,144,142,71,69,67,65,32,30,28,26,13,11,9,7};
        const bool ISCONV[17] = {1,1,0,1,1,0,1,1,1,0,1,1,1,0,1,1,1};
        #pragma unroll
        for (int i = 0; i < 17; i++) {
            if (ISCONV[i]) {
                c0 = max(c0 - 1, 0); c1 = max(c1 - 1, 0);
                c2 = min(c2, XL1[i] - 1); c3 = min(c3, XL1[i] - 1);
            } else {
                c0 >>= 1; c1 >>= 1; c2 >>= 1; c3 >>= 1;
            }
        }
        int xi = c0, yi = c1, xf = c2, yf = c3;
        int wx = xf + 1 - xi, wy = yf + 1 - yi;
        int bx[8], by[8];
        #pragma unroll
        for (int i = 0; i < 8; i++) { bx[i] = xi + fdiv7(i * wx); by[i] = yi + fdiv7(i * wy); }
        int8_t* cr = cells + r * 64;
        #pragma unroll
        for (int i = 0; i < 7; i++)
            #pragma unroll
            for (int j = 0; j < 7; j++) {
                bool ne = valid && (bx[i + 1] > bx[i]) && (by[j + 1] > by[j]);
                cr[i * 7 + j] = ne ? (int8_t)(bx[i] * 7 + by[j]) : (int8_t)(-1);
            }
    } else if (blk < 37) {
        // ---- cfeats -> bf16 [b][xy pad64][c 512] ----
        int g = (blk - 5) * 256 + t;          // 8192 threads
        int b = g >> 12;
        int xy = (g >> 6) & 63;
        int c0 = (g & 63) * 8;
        uint32_t pk[4];
        if (xy < 49) {
            #pragma unroll
            for (int h = 0; h < 4; h++) {
                uint16_t lo = f2bf(cf[(b * 512 + c0 + 2 * h) * 49 + xy]);
                uint16_t hi = f2bf(cf[(b * 512 + c0 + 2 * h + 1) * 49 + xy]);
                pk[h] = (uint32_t)lo | ((uint32_t)hi << 16);
            }
        } else {
            pk[0] = pk[1] = pk[2] = pk[3] = 0;
        }
        ((uint4*)cfb)[(b * 64 + xy) * 64 + (g & 63)] = make_uint4(pk[0], pk[1], pk[2], pk[3]);
    } else if (blk < 175) {
        // ---- small weight transposes ----
        int g = (blk - 37) * 256 + t;
        if (g < 200 * 128) {
            int k = g >> 7, o = g & 127;
            w2t[g] = (o < 100) ? w2[o * 200 + k] : 0.f;
        }
        int u = g - 200 * 128;
        if (u >= 0 && u < 100 * 96) {
            int k = u / 96, o = u - k * 96;
            float v = 0.f;
            if (o < 17) v = w3[o * 100 + k];
            else if (o < 85) v = w4[(o - 17) * 100 + k];
            w34t[u] = v;
        }
    } else {
        // ---- W1 -> fragment-ready bf16 W1f (bf16 staged in LDS, stride 788) ----
        int idx = blk - 175;                 // 0..415
        int nt = idx % 13, ct = idx / 13;    // nt: o-tile of 16; ct: c-tile of 16
        int kbase = ct * 784;
        for (int i = t; i < 16 * 196; i += 256) {
            int rr = i / 196, c4 = i - rr * 196;
            int o = nt * 16 + rr;
            float4 v = make_float4(0.f, 0.f, 0.f, 0.f);
            if (o < 200) v = ((const float4*)(w1 + (size_t)o * 25088 + kbase))[c4];
            ushort4 hv;
            hv.x = f2bf(v.x); hv.y = f2bf(v.y); hv.z = f2bf(v.z); hv.w = f2bf(v.w);
            *(ushort4*)&lh[rr * 788 + 4 * c4] = hv;
        }
        __syncthreads();
        int kc = ct >> 1;
        int q0 = (ct & 1) * 2;
        int lsub = t & 31;
        int l = q0 * 16 + lsub;              // lane within MFMA B-frag
        int rrow = lsub & 15;                // o - nt*16
        int clbase = (lsub >> 4) * 8;        // c offset within this 16-wide c-tile
        for (int binb = 0; binb < 49; binb += 8) {
            int bin = binb + (t >> 5);
            if (bin < 49) {
                uint32_t pk[4];
                #pragma unroll
                for (int h = 0; h < 4; h++) {
                    uint32_t lo = lh[rrow * 788 + (clbase + 2 * h) * 49 + bin];
                    uint32_t hi = lh[rrow * 788 + (clbase + 2 * h + 1) * 49 + bin];
                    pk[h] = lo | (hi << 16);
                }
                ((uint4*)w1f)[((bin * 16 + kc) * 13 + nt) * 64 + l] =
                    make_uint4(pk[0], pk[1], pk[2], pk[3]);
            }
        }
    }
}

// ---------------- G: Q = cfb x W1f. A staged once in LDS (swizzled); each wave owns a bin. ----------------
// grid (13 bg, 13 nt, 2 b). Wave w handles bin = bg*4+w over full M (4 tiles of 16 xy).
__global__ void __launch_bounds__(256) k_qgemm(const uint16_t* __restrict__ cfb,
                                               const uint16_t* __restrict__ w1f,
                                               float* __restrict__ Q) {
    __shared__ uint4 As[64 * 64];   // 64 KB: A[xy][i], i XOR-swizzled by (xy&7)
    int bg = blockIdx.x, nt = blockIdx.y, b = blockIdx.z;
    int t = threadIdx.x;
    const uint4* ac = (const uint4*)cfb + b * 4096;
    for (int idx = t; idx < 4096; idx += 256) {
        int xy = idx >> 6, i = idx & 63;
        As[xy * 64 + (i ^ (xy & 7))] = ac[idx];
    }
    __syncthreads();
    int w = t >> 6, l = t & 63;
    int bin = bg * 4 + w;
    if (bin >= 49) return;    // after the only sync: safe
    int r16 = l & 15, quad = l >> 4;
    int o = nt * 16 + r16;
    int swz = r16 & 7;        // (m*16+r16)&7 == r16&7
    const uint4* bw = (const uint4*)w1f + (bin * 208 + nt) * 64 + l;   // 208 = 16*13
    f32x4 acc[4];
    #pragma unroll
    for (int m = 0; m < 4; m++) acc[m] = (f32x4){0.f, 0.f, 0.f, 0.f};
    #pragma unroll
    for (int kc = 0; kc < 16; kc++) {
        uint4 bv = bw[kc * 832];   // 832 = 13*64
        short8 b8 = __builtin_bit_cast(short8, bv);
        #pragma unroll
        for (int m = 0; m < 4; m++) {
            uint4 av = As[(m * 16 + r16) * 64 + ((kc * 4 + quad) ^ swz)];
            short8 a8 = __builtin_bit_cast(short8, av);
            acc[m] = __builtin_amdgcn_mfma_f32_16x16x32_bf16(a8, b8, acc[m], 0, 0, 0);
        }
    }
    float* qb = Q + ((size_t)(b * 49 + bin) * 49) * 208 + o;
    #pragma unroll
    for (int m = 0; m < 4; m++)
        #pragma unroll
        for (int reg = 0; reg < 4; reg++) {
            int xy = m * 16 + quad * 4 + reg;
            if (xy < 49) qb[xy * 208] = acc[m][reg];
        }
}

// ---------------- F: gather + MLP head, 5 ROIs per block (weights read once per block) ----------------
__global__ void __launch_bounds__(256) k_head(const int8_t* __restrict__ cells,
                                              const float* __restrict__ Q,
                                              const float* __restrict__ b1,
                                              const float* __restrict__ w2t,
                                              const float* __restrict__ b2,
                                              const float* __restrict__ w34t,
                                              const float* __restrict__ b3,
                                              const float* __restrict__ b4,
                                              float* __restrict__ out) {
    __shared__ float z1s[5][200];
    __shared__ float z2s[5][100];
    __shared__ float zps[5][256];
    __shared__ int8_t cls[5 * 64];
    int r0 = blockIdx.x * 5;          // 625%5==0: all 5 ROIs share b
    int b = r0 / 625;
    int t = threadIdx.x;
    for (int i = t; i < 80; i += 256)
        ((uint32_t*)cls)[i] = ((const uint32_t*)(cells + r0 * 64))[i];
    __syncthreads();
    float s[5] = {0.f, 0.f, 0.f, 0.f, 0.f};
    if (t < 208) {
        const float* qb = Q + (size_t)(b * 49) * 49 * 208 + t;
        #pragma unroll 7
        for (int bin = 0; bin < 49; bin++) {
            #pragma unroll
            for (int roi = 0; roi < 5; roi++) {
                int cv = (int)cls[roi * 64 + bin];
                int idx = max(cv, 0);
                float m = (cv >= 0) ? 1.f : 0.f;
                s[roi] += m * qb[(bin * 49 + idx) * 208];
            }
        }
    }
    if (t < 200) {
        float bb = b1[t];
        #pragma unroll
        for (int roi = 0; roi < 5; roi++) z1s[roi][t] = fmaxf(s[roi] + bb, 0.f);
    }
    __syncthreads();
    int o2 = t & 127, kq = t >> 7;    // 2-way split-k
    float a[5] = {0.f, 0.f, 0.f, 0.f, 0.f};
    if (o2 < 100) {
        const float* wp = w2t + (kq * 100) * 128 + o2;
        #pragma unroll 4
        for (int k = 0; k < 100; k++) {
            float wv = wp[k * 128];
            #pragma unroll
            for (int roi = 0; roi < 5; roi++) a[roi] += z1s[roi][kq * 100 + k] * wv;
        }
    }
    #pragma unroll
    for (int roi = 0; roi < 5; roi++) zps[roi][t] = a[roi];
    __syncthreads();
    if (t < 100) {
        float bb = b2[t];
        #pragma unroll
        for (int roi = 0; roi < 5; roi++)
            z2s[roi][t] = fmaxf(bb + zps[roi][t] + zps[roi][t + 128], 0.f);
    }
    __syncthreads();
    float c[5] = {0.f, 0.f, 0.f, 0.f, 0.f};
    if (o2 < 85) {
        const float* wp = w34t + (kq * 50) * 96 + o2;
        #pragma unroll 5
        for (int k = 0; k < 50; k++) {
            float wv = wp[k * 96];
            #pragma unroll
            for (int roi = 0; roi < 5; roi++) c[roi] += z2s[roi][kq * 50 + k] * wv;
        }
    }
    __syncthreads();                  // all z2s reads done before zps reuse
    #pragma unroll
    for (int roi = 0; roi < 5; roi++) zps[roi][t] = c[roi];
    __syncthreads();
    if (t < 85) {
        float bb = (t < 17) ? b3[t] : b4[t - 17];
        #pragma unroll
        for (int roi = 0; roi < 5; roi++) {
            int n = r0 + roi - b * 625;
            float v = bb + zps[roi][t] + zps[roi][t + 128];
            if (t < 17) {
                out[b * 10625 + n * 17 + t] = v;
            } else {
                int q = (t - 17) / 17, kk = (t - 17) - q * 17;
                out[21250 + b * 42500 + q * 10625 + n * 17 + kk] = v;
            }
        }
    }
}

extern "C" void kernel_launch(void* const* d_in, const int* in_sizes, int n_in,
                              void* d_out, int out_size, void* d_ws, size_t ws_size,
                              hipStream_t stream) {
    const float* cfeats = (const float*)d_in[0];
    const float* regcls = (const float*)d_in[1];
    const float* wan    = (const float*)d_in[2];
    const float* han    = (const float*)d_in[3];
    const float* xan    = (const float*)d_in[4];
    const float* yan    = (const float*)d_in[5];
    const float* w1     = (const float*)d_in[6];
    const float* b1     = (const float*)d_in[7];
    const float* w2     = (const float*)d_in[8];
    const float* b2     = (const float*)d_in[9];
    const float* w3     = (const float*)d_in[10];
    const float* b3     = (const float*)d_in[11];
    const float* w4     = (const float*)d_in[12];
    const float* b4     = (const float*)d_in[13];

    char* ws = (char*)d_ws;
    int8_t*   cells = (int8_t*)ws;                    //     80,000 B
    uint16_t* cfb   = (uint16_t*)(ws + 80000);        //    131,072 B
    uint16_t* w1f   = (uint16_t*)(ws + 211072);       // 10,436,608 B
    float*    Q     = (float*)(ws + 10647680);        //  3,995,264 B
    float*    w2t   = (float*)(ws + 14642944);        //    102,400 B
    float*    w34t  = (float*)(ws + 14745344);        //     38,400 B
    float*    out   = (float*)d_out;

    k_prep<<<dim3(591), dim3(256), 0, stream>>>(regcls, wan, han, xan, yan,
                                                cfeats, w1, w2, w3, w4,
                                                cells, cfb, w1f, w2t, w34t);
    k_qgemm<<<dim3(13, 13, 2), dim3(256), 0, stream>>>(cfb, w1f, Q);
    k_head<<<dim3(250), dim3(256), 0, stream>>>(cells, Q, b1, w2t, b2, w34t, b3, b4, out);
}

// Round 8
// 122.095 us; speedup vs baseline: 1.0811x; 1.0811x over previous
//
#include <hip/hip_runtime.h>
#include <cstdint>

using short8 = __attribute__((ext_vector_type(8))) short;
using f32x4  = __attribute__((ext_vector_type(4))) float;

__device__ __forceinline__ uint16_t f2bf(float x) {
    uint32_t u = __float_as_uint(x);
    uint32_t r = (u + 0x7FFFu + ((u >> 16) & 1u)) >> 16;
    return (uint16_t)r;
}
__device__ __forceinline__ int fdiv7(int a) {
    int q = a / 7;
    if ((a % 7 != 0) && (a < 0)) q--;
    return q;
}

// ---------------- merged prep: decode | cfb | wsmall | w1f (round-6/7 verified, unchanged) ----------------
__global__ void __launch_bounds__(256) k_prep(const float* __restrict__ regcls,
                                              const float* __restrict__ wan,
                                              const float* __restrict__ han,
                                              const float* __restrict__ xan,
                                              const float* __restrict__ yan,
                                              const float* __restrict__ cf,
                                              const float* __restrict__ w1,
                                              const float* __restrict__ w2,
                                              const float* __restrict__ w3,
                                              const float* __restrict__ w4,
                                              int8_t* __restrict__ cells,
                                              uint16_t* __restrict__ cfb,
                                              uint16_t* __restrict__ w1f,
                                              float* __restrict__ w2t,
                                              float* __restrict__ w34t) {
    __shared__ __align__(16) uint16_t lh[16 * 788];   // 25,216 B (w1f branch only)
    int blk = blockIdx.x;
    int t = threadIdx.x;

    if (blk < 5) {
        // ---- ROI decode ----
        int r = blk * 256 + t;
        if (r >= 1250) return;
        int b = r / 625, n = r - b * 625;
        const float* rc = regcls + b * 3125 + n;
        float t0 = rc[0], t1 = rc[625], t2 = rc[1250], t3 = rc[1875];
        float wa = wan[n], ha = han[n], xa = xan[n], ya = yan[n];
        float wr = expf(t2) * wa, hr = expf(t3) * ha;
        float xr = t0 * wa + xa, yr = t1 * ha + ya;
        float xis = xr - wr * 0.5f, yis = yr - hr * 0.5f;
        float xfs = xr + wr * 0.5f, yfs = yr + hr * 0.5f;
        bool valid = (xis < 296.f) && (yis < 296.f) && (xfs >= 0.f) && (yfs >= 0.f);
        int c0 = (int)floorf(fmaxf(xis, 0.f));
        int c1 = (int)floorf(fmaxf(yis, 0.f));
        int c2 = (int)fminf(ceilf(xfs), 295.f);
        int c3 = (int)fmaxf(ceilf(yfs), 295.f);
        const int  XL1[17]    = {294,292,146,144,142,71,69,67,65,32,30,28,26,13,11,9,7};
        const bool ISCONV[17] = {1,1,0,1,1,0,1,1,1,0,1,1,1,0,1,1,1};
        #pragma unroll
        for (int i = 0; i < 17; i++) {
            if (ISCONV[i]) {
                c0 = max(c0 - 1, 0); c1 = max(c1 - 1, 0);
                c2 = min(c2, XL1[i] - 1); c3 = min(c3, XL1[i] - 1);
            } else {
                c0 >>= 1; c1 >>= 1; c2 >>= 1; c3 >>= 1;
            }
        }
        int xi = c0, yi = c1, xf = c2, yf = c3;
        int wx = xf + 1 - xi, wy = yf + 1 - yi;
        int bx[8], by[8];
        #pragma unroll
        for (int i = 0; i < 8; i++) { bx[i] = xi + fdiv7(i * wx); by[i] = yi + fdiv7(i * wy); }
        int8_t* cr = cells + r * 64;
        #pragma unroll
        for (int i = 0; i < 7; i++)
            #pragma unroll
            for (int j = 0; j < 7; j++) {
                bool ne = valid && (bx[i + 1] > bx[i]) && (by[j + 1] > by[j]);
                cr[i * 7 + j] = ne ? (int8_t)(bx[i] * 7 + by[j]) : (int8_t)(-1);
            }
    } else if (blk < 37) {
        // ---- cfeats -> bf16 [b][xy pad64][c 512] ----
        int g = (blk - 5) * 256 + t;          // 8192 threads
        int b = g >> 12;
        int xy = (g >> 6) & 63;
        int c0 = (g & 63) * 8;
        uint32_t pk[4];
        if (xy < 49) {
            #pragma unroll
            for (int h = 0; h < 4; h++) {
                uint16_t lo = f2bf(cf[(b * 512 + c0 + 2 * h) * 49 + xy]);
                uint16_t hi = f2bf(cf[(b * 512 + c0 + 2 * h + 1) * 49 + xy]);
                pk[h] = (uint32_t)lo | ((uint32_t)hi << 16);
            }
        } else {
            pk[0] = pk[1] = pk[2] = pk[3] = 0;
        }
        ((uint4*)cfb)[(b * 64 + xy) * 64 + (g & 63)] = make_uint4(pk[0], pk[1], pk[2], pk[3]);
    } else if (blk < 175) {
        // ---- small weight transposes ----
        int g = (blk - 37) * 256 + t;
        if (g < 200 * 128) {
            int k = g >> 7, o = g & 127;
            w2t[g] = (o < 100) ? w2[o * 200 + k] : 0.f;
        }
        int u = g - 200 * 128;
        if (u >= 0 && u < 100 * 96) {
            int k = u / 96, o = u - k * 96;
            float v = 0.f;
            if (o < 17) v = w3[o * 100 + k];
            else if (o < 85) v = w4[(o - 17) * 100 + k];
            w34t[u] = v;
        }
    } else {
        // ---- W1 -> fragment-ready bf16 W1f (bf16 staged in LDS, stride 788) ----
        int idx = blk - 175;                 // 0..415
        int nt = idx % 13, ct = idx / 13;    // nt: o-tile of 16; ct: c-tile of 16
        int kbase = ct * 784;
        for (int i = t; i < 16 * 196; i += 256) {
            int rr = i / 196, c4 = i - rr * 196;
            int o = nt * 16 + rr;
            float4 v = make_float4(0.f, 0.f, 0.f, 0.f);
            if (o < 200) v = ((const float4*)(w1 + (size_t)o * 25088 + kbase))[c4];
            ushort4 hv;
            hv.x = f2bf(v.x); hv.y = f2bf(v.y); hv.z = f2bf(v.z); hv.w = f2bf(v.w);
            *(ushort4*)&lh[rr * 788 + 4 * c4] = hv;
        }
        __syncthreads();
        int kc = ct >> 1;
        int q0 = (ct & 1) * 2;
        int lsub = t & 31;
        int l = q0 * 16 + lsub;              // lane within MFMA B-frag
        int rrow = lsub & 15;                // o - nt*16
        int clbase = (lsub >> 4) * 8;        // c offset within this 16-wide c-tile
        for (int binb = 0; binb < 49; binb += 8) {
            int bin = binb + (t >> 5);
            if (bin < 49) {
                uint32_t pk[4];
                #pragma unroll
                for (int h = 0; h < 4; h++) {
                    uint32_t lo = lh[rrow * 788 + (clbase + 2 * h) * 49 + bin];
                    uint32_t hi = lh[rrow * 788 + (clbase + 2 * h + 1) * 49 + bin];
                    pk[h] = lo | (hi << 16);
                }
                ((uint4*)w1f)[((bin * 16 + kc) * 13 + nt) * 64 + l] =
                    make_uint4(pk[0], pk[1], pk[2], pk[3]);
            }
        }
    }
}

// ---------------- G: Q = cfb x W1f. A staged once in LDS (swizzled); each wave owns a bin. ----------------
// grid (13 bg, 13 nt, 2 b). Wave w handles bin = bg*4+w over full M (4 tiles of 16 xy).
// No launch_bounds: free VGPR budget for deeper load pipelining.
__global__ void k_qgemm(const uint16_t* __restrict__ cfb,
                        const uint16_t* __restrict__ w1f,
                        float* __restrict__ Q) {
    __shared__ uint4 As[64 * 64];   // 64 KB: A[xy][i], i XOR-swizzled by (xy&7)
    int bg = blockIdx.x, nt = blockIdx.y, b = blockIdx.z;
    int t = threadIdx.x;
    const uint4* ac = (const uint4*)cfb + b * 4096;
    for (int idx = t; idx < 4096; idx += 256) {
        int xy = idx >> 6, i = idx & 63;
        As[xy * 64 + (i ^ (xy & 7))] = ac[idx];
    }
    __syncthreads();
    int w = t >> 6, l = t & 63;
    int bin = bg * 4 + w;
    if (bin >= 49) return;    // after the only sync: safe
    int r16 = l & 15, quad = l >> 4;
    int o = nt * 16 + r16;
    int swz = r16 & 7;        // (m*16+r16)&7 == r16&7
    const uint4* bw = (const uint4*)w1f + (bin * 208 + nt) * 64 + l;   // 208 = 16*13
    f32x4 acc[4];
    #pragma unroll
    for (int m = 0; m < 4; m++) acc[m] = (f32x4){0.f, 0.f, 0.f, 0.f};
    #pragma unroll
    for (int kc = 0; kc < 16; kc++) {
        uint4 bv = bw[kc * 832];   // 832 = 13*64
        short8 b8 = __builtin_bit_cast(short8, bv);
        #pragma unroll
        for (int m = 0; m < 4; m++) {
            uint4 av = As[(m * 16 + r16) * 64 + ((kc * 4 + quad) ^ swz)];
            short8 a8 = __builtin_bit_cast(short8, av);
            acc[m] = __builtin_amdgcn_mfma_f32_16x16x32_bf16(a8, b8, acc[m], 0, 0, 0);
        }
    }
    float* qb = Q + ((size_t)(b * 49 + bin) * 49) * 208 + o;
    #pragma unroll
    for (int m = 0; m < 4; m++)
        #pragma unroll
        for (int reg = 0; reg < 4; reg++) {
            int xy = m * 16 + quad * 4 + reg;
            if (xy < 49) qb[xy * 208] = acc[m][reg];
        }
}

// ---------------- F: per-ROI gather-sum over Q + fused 3-layer MLP head (2-way split-k) ----------------
// 1 ROI per block (1250 blocks: 4-6 blocks/CU for latency hiding). No launch_bounds:
// free VGPRs let the compiler keep many of the 49 independent gather loads in flight.
__global__ void k_head(const int8_t* __restrict__ cells,
                       const float* __restrict__ Q,
                       const float* __restrict__ b1,
                       const float* __restrict__ w2t,
                       const float* __restrict__ b2,
                       const float* __restrict__ w34t,
                       const float* __restrict__ b3,
                       const float* __restrict__ b4,
                       float* __restrict__ out) {
    __shared__ float z1[200];
    __shared__ float z2[100];
    __shared__ float zp[256];
    int r = blockIdx.x;
    int b = r / 625, n = r - b * 625;
    int t = threadIdx.x;
    int o2 = t & 127, kq = t >> 7;     // 2-way split-k lanes
    const int8_t* cr = cells + r * 64;
    float s[4] = {0.f, 0.f, 0.f, 0.f};
    if (t < 208) {
        const float* qb = Q + (size_t)(b * 49) * 49 * 208 + t;
        // branchless, fully unrolled: 49 independent L2 loads, 4 accumulator chains
        #pragma unroll
        for (int bin = 0; bin < 49; bin++) {
            int cv = (int)cr[bin];
            int idx = max(cv, 0);
            float m = (cv >= 0) ? 1.f : 0.f;
            s[bin & 3] += m * qb[(bin * 49 + idx) * 208];
        }
    }
    if (t < 200) z1[t] = fmaxf(s[0] + s[1] + s[2] + s[3] + b1[t], 0.f);
    __syncthreads();
    // layer 2: 100 outputs x 2 k-halves of 100
    float a0 = 0.f, a1 = 0.f;
    if (o2 < 100) {
        const float* wp = w2t + (kq * 100) * 128 + o2;
        const float* zz = z1 + kq * 100;
        #pragma unroll 10
        for (int k = 0; k < 100; k += 2) {
            a0 += zz[k]     * wp[k * 128];
            a1 += zz[k + 1] * wp[(k + 1) * 128];
        }
    }
    zp[t] = a0 + a1;
    __syncthreads();
    if (t < 100) z2[t] = fmaxf(b2[t] + zp[t] + zp[t + 128], 0.f);
    __syncthreads();
    // layer 3/4: 85 outputs x 2 k-halves of 50
    float c0 = 0.f;
    if (o2 < 85) {
        const float* wp = w34t + (kq * 50) * 96 + o2;
        const float* zz = z2 + kq * 50;
        #pragma unroll 10
        for (int k = 0; k < 50; k++) c0 += zz[k] * wp[k * 96];
    }
    zp[t] = c0;
    __syncthreads();
    if (t < 85) {
        float v = ((t < 17) ? b3[t] : b4[t - 17]) + zp[t] + zp[t + 128];
        if (t < 17) {
            out[b * 10625 + n * 17 + t] = v;
        } else {
            int q = (t - 17) / 17, kk = (t - 17) - q * 17;
            out[21250 + b * 42500 + q * 10625 + n * 17 + kk] = v;
        }
    }
}

extern "C" void kernel_launch(void* const* d_in, const int* in_sizes, int n_in,
                              void* d_out, int out_size, void* d_ws, size_t ws_size,
                              hipStream_t stream) {
    const float* cfeats = (const float*)d_in[0];
    const float* regcls = (const float*)d_in[1];
    const float* wan    = (const float*)d_in[2];
    const float* han    = (const float*)d_in[3];
    const float* xan    = (const float*)d_in[4];
    const float* yan    = (const float*)d_in[5];
    const float* w1     = (const float*)d_in[6];
    const float* b1     = (const float*)d_in[7];
    const float* w2     = (const float*)d_in[8];
    const float* b2     = (const float*)d_in[9];
    const float* w3     = (const float*)d_in[10];
    const float* b3     = (const float*)d_in[11];
    const float* w4     = (const float*)d_in[12];
    const float* b4     = (const float*)d_in[13];

    char* ws = (char*)d_ws;
    int8_t*   cells = (int8_t*)ws;                    //     80,000 B
    uint16_t* cfb   = (uint16_t*)(ws + 80000);        //    131,072 B
    uint16_t* w1f   = (uint16_t*)(ws + 211072);       // 10,436,608 B
    float*    Q     = (float*)(ws + 10647680);        //  3,995,264 B
    float*    w2t   = (float*)(ws + 14642944);        //    102,400 B
    float*    w34t  = (float*)(ws + 14745344);        //     38,400 B
    float*    out   = (float*)d_out;

    k_prep<<<dim3(591), dim3(256), 0, stream>>>(regcls, wan, han, xan, yan,
                                                cfeats, w1, w2, w3, w4,
                                                cells, cfb, w1f, w2t, w34t);
    k_qgemm<<<dim3(13, 13, 2), dim3(256), 0, stream>>>(cfb, w1f, Q);
    k_head<<<dim3(1250), dim3(256), 0, stream>>>(cells, Q, b1, w2t, b2, w34t, b3, b4, out);
}